// Round 8
// baseline (106.977 us; speedup 1.0000x reference)
//
#include <hip/hip_runtime.h>
#include <hip/hip_bf16.h>

#define NB 16
#define NT 2048
#define NDM 1024
#define NDK 128

typedef __bf16 bf16;
typedef bf16 bf16x4 __attribute__((ext_vector_type(4)));
typedef bf16 bf16x8 __attribute__((ext_vector_type(8)));
typedef float f32x4 __attribute__((ext_vector_type(4)));

__device__ inline bf16 to_bf16(float f) {
    __hip_bfloat16 h = __float2bfloat16(f);
    return *reinterpret_cast<bf16*>(&h);
}

// ---------------------------------------------------------------------------
// Kernel 1: W [1024][128] f32  ->  Wt bf16 [3][128][1024]  (transposed, K-major)
// ---------------------------------------------------------------------------
__global__ __launch_bounds__(256) void transpose_w_kernel(
        const float* __restrict__ Wq, const float* __restrict__ Wk,
        const float* __restrict__ Wv, bf16* __restrict__ Wt) {
    int idx = blockIdx.x * 256 + threadIdx.x;      // over 3*1024*128
    int w = idx >> 17;                             // / (1024*128)
    int r = idx & (NDM * NDK - 1);
    int k = r >> 7;                                // / 128
    int n = r & (NDK - 1);
    const float* W = (w == 0) ? Wq : ((w == 1) ? Wk : Wv);
    Wt[(size_t)w * NDK * NDM + (size_t)n * NDM + k] = to_bf16(W[(size_t)k * NDK + n]);
}

// ---------------------------------------------------------------------------
// Kernel 2: QKV projection — R2-proven structure (occupancy-first: 20.5 KB LDS,
// VGPR ~80 -> ~6 blocks/CU; latency hidden by cross-block wave overlap).
// ---------------------------------------------------------------------------
__global__ __launch_bounds__(256) void proj_kernel(
        const float* __restrict__ x, const bf16* __restrict__ Wt,
        bf16* __restrict__ qkv) {
    __shared__ bf16 As[128][40];
    __shared__ bf16 Bs[128][40];   // [n][k]
    const int tid = threadIdx.x;
    const int lane = tid & 63;
    const int wave = tid >> 6;
    const int wr = wave >> 1, wc = wave & 1;
    const int r16 = lane & 15, kg = lane >> 4;
    const int mb = blockIdx.x;
    const int w = blockIdx.y;
    const float* xA = x + (size_t)mb * 128 * NDM;
    const bf16* Bt = Wt + (size_t)w * NDK * NDM;

    f32x4 acc[4][4];
#pragma unroll
    for (int m = 0; m < 4; m++)
#pragma unroll
        for (int n = 0; n < 4; n++) acc[m][n] = (f32x4){0.f, 0.f, 0.f, 0.f};

    for (int k0 = 0; k0 < NDM; k0 += 32) {
        // stage A: 128x32 f32 -> bf16
#pragma unroll
        for (int p = 0; p < 4; p++) {
            int row = p * 32 + (tid >> 3);
            int c4 = (tid & 7) * 4;
            const float4 v = *reinterpret_cast<const float4*>(&xA[(size_t)row * NDM + k0 + c4]);
            bf16x4 bv = { to_bf16(v.x), to_bf16(v.y), to_bf16(v.z), to_bf16(v.w) };
            *reinterpret_cast<bf16x4*>(&As[row][c4]) = bv;
        }
        // stage B: 128x32 bf16 (already K-contiguous)
#pragma unroll
        for (int p = 0; p < 2; p++) {
            int idx = (p * 256 + tid) * 8;
            int n = idx >> 5;
            int kk = idx & 31;
            *reinterpret_cast<bf16x8*>(&Bs[n][kk]) =
                *reinterpret_cast<const bf16x8*>(&Bt[(size_t)n * NDM + k0 + kk]);
        }
        __syncthreads();
        bf16x8 af[4], bfr[4];
#pragma unroll
        for (int m = 0; m < 4; m++)
            af[m] = *reinterpret_cast<const bf16x8*>(&As[wr * 64 + m * 16 + r16][kg * 8]);
#pragma unroll
        for (int n = 0; n < 4; n++)
            bfr[n] = *reinterpret_cast<const bf16x8*>(&Bs[wc * 64 + n * 16 + r16][kg * 8]);
#pragma unroll
        for (int m = 0; m < 4; m++)
#pragma unroll
            for (int n = 0; n < 4; n++)
                acc[m][n] = __builtin_amdgcn_mfma_f32_16x16x32_bf16(af[m], bfr[n], acc[m][n], 0, 0, 0);
        __syncthreads();
    }

    bf16* outw = qkv + (size_t)w * (size_t)(NB * NT) * NDK;
#pragma unroll
    for (int m = 0; m < 4; m++) {
        int rowb = mb * 128 + wr * 64 + m * 16 + kg * 4;
#pragma unroll
        for (int n = 0; n < 4; n++) {
            int col = wc * 64 + n * 16 + r16;
#pragma unroll
            for (int r = 0; r < 4; r++)
                outw[(size_t)(rowb + r) * NDK + col] = to_bf16(acc[m][n][r]);
        }
    }
}

// ---------------------------------------------------------------------------
// Kernel 2.5: V [B][T][128] bf16 -> Vt [B][128][T] bf16 (one-time transpose)
// ---------------------------------------------------------------------------
__global__ __launch_bounds__(256) void transpose_v_kernel(
        const bf16* __restrict__ V, bf16* __restrict__ Vt) {
    __shared__ bf16 Tl[64][136];   // [t][d], padded
    const int tid = threadIdx.x;
    const int tb = blockIdx.x, b = blockIdx.y;
    const int t0 = tb * 64;
    const size_t ibase = (size_t)b * NT * NDK;
    const size_t obase = (size_t)b * NDK * NT;
#pragma unroll
    for (int p = 0; p < 4; p++) {
        int idx = p * 256 + tid;           // chunk over 64 rows x 16 chunks
        int row = idx >> 4, c = idx & 15;
        *reinterpret_cast<bf16x8*>(&Tl[row][c * 8]) =
            *reinterpret_cast<const bf16x8*>(&V[ibase + (size_t)(t0 + row) * NDK + c * 8]);
    }
    __syncthreads();
#pragma unroll
    for (int p = 0; p < 4; p++) {
        int idx = p * 256 + tid;           // chunk over 128 d-rows x 8 chunks
        int d = idx >> 3, c = idx & 7;
        bf16x8 v;
#pragma unroll
        for (int j = 0; j < 8; j++) v[j] = Tl[c * 8 + j][d];
        *reinterpret_cast<bf16x8*>(&Vt[obase + (size_t)d * NT + t0 + c * 8]) = v;
    }
}

// ---------------------------------------------------------------------------
// Kernel 3: causal flash attention, swapped-QK^T softmax (S^T = K·Q^T so each
// lane owns one q-row's kv-slice -> in-lane reductions). K/V LDS double-
// buffered, one barrier per step, reg-prefetch 1 tile ahead (T14).
// ---------------------------------------------------------------------------
__global__ __launch_bounds__(256) void attn_kernel(
        const bf16* __restrict__ Q, const bf16* __restrict__ K,
        const bf16* __restrict__ Vt, float* __restrict__ out) {
    __shared__ bf16 Ks[2][64][128];   // [buf][kv][k], swizzled
    __shared__ bf16 Vs[2][128][64];   // [buf][d][kv], swizzled
    __shared__ bf16 Ps[4][16][72];    // [wave][q-local][kv], padded
    const int tid = threadIdx.x, lane = tid & 63, wave = tid >> 6;
    const int r16 = lane & 15, kg = lane >> 4;

    // XCD-aware mapping: each XCD owns 2 batches (KV working set 2MB < L2)
    const int bid = blockIdx.x;
    const int xcd = bid & 7;
    const int j = bid >> 3;
    const int b = xcd * 2 + (j & 1);
    const int qb = (NT / 64 - 1) - (j >> 1);   // longest first
    const int q0 = qb * 64;
    const size_t baseB = (size_t)b * NT * NDK;
    const size_t baseVt = (size_t)b * NDK * NT;

    const float scale = 0.08838834764831843f;  // 1/sqrt(128)
    bf16x8 qf[4];
    const int qglob = q0 + wave * 16 + r16;    // this lane's q-row
#pragma unroll
    for (int kc = 0; kc < 4; kc++) {
        bf16x8 raw = *reinterpret_cast<const bf16x8*>(&Q[baseB + (size_t)qglob * NDK + kc * 32 + kg * 8]);
#pragma unroll
        for (int jj = 0; jj < 8; jj++) raw[jj] = to_bf16((float)raw[jj] * scale);
        qf[kc] = raw;
    }

    f32x4 o[8];
#pragma unroll
    for (int n = 0; n < 8; n++) o[n] = (f32x4){0.f, 0.f, 0.f, 0.f};
    float mrun = -INFINITY;   // running max for q = qglob
    float lrun = 0.f;         // running denom

    int krow[4], kcol[4], vrow[4], vcol[4];
#pragma unroll
    for (int i = 0; i < 4; i++) {
        int idx = i * 256 + tid;
        krow[i] = idx >> 4; kcol[i] = idx & 15;   // 64 rows x 16 chunks
        vrow[i] = idx >> 3; vcol[i] = idx & 7;    // 128 rows x 8 chunks
    }

    const int nsteps = qb + 1;
    bf16x8 kreg[4], vreg[4];
    // prologue: tile 0 -> regs -> buf0; issue tile 1 loads
#pragma unroll
    for (int i = 0; i < 4; i++) {
        kreg[i] = *reinterpret_cast<const bf16x8*>(&K[baseB + (size_t)krow[i] * NDK + kcol[i] * 8]);
        vreg[i] = *reinterpret_cast<const bf16x8*>(&Vt[baseVt + (size_t)vrow[i] * NT + vcol[i] * 8]);
    }
#pragma unroll
    for (int i = 0; i < 4; i++) {
        *reinterpret_cast<bf16x8*>(&Ks[0][krow[i]][(kcol[i] ^ (krow[i] & 7)) * 8]) = kreg[i];
        *reinterpret_cast<bf16x8*>(&Vs[0][vrow[i]][(vcol[i] ^ (vrow[i] & 7)) * 8]) = vreg[i];
    }
    if (nsteps > 1) {
#pragma unroll
        for (int i = 0; i < 4; i++) {
            kreg[i] = *reinterpret_cast<const bf16x8*>(&K[baseB + (size_t)(64 + krow[i]) * NDK + kcol[i] * 8]);
            vreg[i] = *reinterpret_cast<const bf16x8*>(&Vt[baseVt + (size_t)vrow[i] * NT + 64 + vcol[i] * 8]);
        }
    }
    __syncthreads();

    for (int s = 0; s < nsteps; s++) {
        const int cur = s & 1;
        const int kv0 = s * 64;

        // S^T = K Q^T : D[kv][q], q = r16 (lane-local row), kv = n*16+kg*4+r
        f32x4 sfr[4];
#pragma unroll
        for (int n = 0; n < 4; n++) sfr[n] = (f32x4){0.f, 0.f, 0.f, 0.f};
#pragma unroll
        for (int n = 0; n < 4; n++) {
            const int krw = n * 16 + r16;
#pragma unroll
            for (int kc = 0; kc < 4; kc++) {
                bf16x8 kf = *reinterpret_cast<const bf16x8*>(&Ks[cur][krw][((kc * 4 + kg) ^ (krw & 7)) * 8]);
                sfr[n] = __builtin_amdgcn_mfma_f32_16x16x32_bf16(kf, qf[kc], sfr[n], 0, 0, 0);
            }
        }

        // causal mask only on diagonal tile: kv > q
        if (s == nsteps - 1) {
#pragma unroll
            for (int n = 0; n < 4; n++)
#pragma unroll
                for (int r = 0; r < 4; r++)
                    if (kv0 + n * 16 + kg * 4 + r > qglob) sfr[n][r] = -INFINITY;
        }

        // tile max: 15 in-lane + 2 cross-kg shuffles
        float pm = -INFINITY;
#pragma unroll
        for (int n = 0; n < 4; n++) {
            float t0 = fmaxf(fmaxf(sfr[n][0], sfr[n][1]), fmaxf(sfr[n][2], sfr[n][3]));
            pm = fmaxf(pm, t0);
        }
        pm = fmaxf(pm, __shfl_xor(pm, 16, 64));
        pm = fmaxf(pm, __shfl_xor(pm, 32, 64));

        // rescale O only if running max grew
        if (__any(pm > mrun)) {
            float mnew = fmaxf(mrun, pm);
            float corr = __expf(mrun - mnew);
            mrun = mnew;
            lrun *= corr;
            float co[4];
#pragma unroll
            for (int r = 0; r < 4; r++) co[r] = __shfl(corr, kg * 4 + r, 64);
#pragma unroll
            for (int n = 0; n < 8; n++)
#pragma unroll
                for (int r = 0; r < 4; r++) o[n][r] *= co[r];
        }

        // P = exp(S - m): in-lane sum, pack 4 bf16 per ds_write_b64
        float ps = 0.f;
#pragma unroll
        for (int n = 0; n < 4; n++) {
            bf16x4 pw;
#pragma unroll
            for (int r = 0; r < 4; r++) {
                float pv = __expf(sfr[n][r] - mrun);
                ps += pv;
                pw[r] = to_bf16(pv);
            }
            *reinterpret_cast<bf16x4*>(&Ps[wave][r16][n * 16 + kg * 4]) = pw;
        }
        ps += __shfl_xor(ps, 16, 64);
        ps += __shfl_xor(ps, 32, 64);
        lrun += ps;

        // O += P V
#pragma unroll
        for (int kc2 = 0; kc2 < 2; kc2++) {
            bf16x8 pf = *reinterpret_cast<const bf16x8*>(&Ps[wave][r16][kc2 * 32 + kg * 8]);
#pragma unroll
            for (int n = 0; n < 8; n++) {
                const int vrw = n * 16 + r16;
                bf16x8 vf = *reinterpret_cast<const bf16x8*>(&Vs[cur][vrw][((kc2 * 4 + kg) ^ (vrw & 7)) * 8]);
                o[n] = __builtin_amdgcn_mfma_f32_16x16x32_bf16(pf, vf, o[n], 0, 0, 0);
            }
        }

        // stage tile s+1 into the other buffer; issue loads for s+2
        if (s + 1 < nsteps) {
#pragma unroll
            for (int i = 0; i < 4; i++) {
                *reinterpret_cast<bf16x8*>(&Ks[1 - cur][krow[i]][(kcol[i] ^ (krow[i] & 7)) * 8]) = kreg[i];
                *reinterpret_cast<bf16x8*>(&Vs[1 - cur][vrow[i]][(vcol[i] ^ (vrow[i] & 7)) * 8]) = vreg[i];
            }
            if (s + 2 < nsteps) {
                const int kv2 = (s + 2) * 64;
#pragma unroll
                for (int i = 0; i < 4; i++) {
                    kreg[i] = *reinterpret_cast<const bf16x8*>(&K[baseB + (size_t)(kv2 + krow[i]) * NDK + kcol[i] * 8]);
                    vreg[i] = *reinterpret_cast<const bf16x8*>(&Vt[baseVt + (size_t)vrow[i] * NT + kv2 + vcol[i] * 8]);
                }
            }
        }
        __syncthreads();
    }

    float linv = 1.0f / lrun;
    float li[4];
#pragma unroll
    for (int r = 0; r < 4; r++) li[r] = __shfl(linv, kg * 4 + r, 64);
#pragma unroll
    for (int n = 0; n < 8; n++)
#pragma unroll
        for (int r = 0; r < 4; r++) {
            int row = q0 + wave * 16 + kg * 4 + r;
            int col = n * 16 + r16;
            out[baseB + (size_t)row * NDK + col] = o[n][r] * li[r];
        }
}

// ---------------------------------------------------------------------------
extern "C" void kernel_launch(void* const* d_in, const int* in_sizes, int n_in,
                              void* d_out, int out_size, void* d_ws, size_t ws_size,
                              hipStream_t stream) {
    const float* x  = (const float*)d_in[0];
    const float* Wq = (const float*)d_in[1];
    const float* Wk = (const float*)d_in[2];
    const float* Wv = (const float*)d_in[3];
    float* out = (float*)d_out;

    char* ws = (char*)d_ws;
    bf16* Wt  = (bf16*)ws;                        // 3*128*1024*2  = 768 KB
    bf16* qkv = (bf16*)(ws + (1ull << 20));       // Q,K,V planes: 24 MB
    bf16* Vtg = (bf16*)(ws + (26ull << 20));      // V^T [B][128][T]: 8 MB

    // 1) transpose weights to bf16 [3][128][1024]
    transpose_w_kernel<<<(3 * NDM * NDK) / 256, 256, 0, stream>>>(Wq, Wk, Wv, Wt);

    // 2) QKV projection (R2-proven high-occupancy structure)
    dim3 g1((NB * NT) / 128, 3);
    proj_kernel<<<g1, 256, 0, stream>>>(x, Wt, qkv);

    bf16* Qp = qkv;
    bf16* Kp = qkv + (size_t)(NB * NT) * NDK;
    bf16* Vp = qkv + 2 * (size_t)(NB * NT) * NDK;

    // 2.5) one-time V transpose -> [B][128][T]
    dim3 gt(NT / 64, NB);
    transpose_v_kernel<<<gt, 256, 0, stream>>>(Vp, Vtg);

    // 3) causal flash attention (1-D grid, XCD-aware mapping inside)
    attn_kernel<<<dim3((NT / 64) * NB), 256, 0, stream>>>(Qp, Kp, Vtg, out);
}

// Round 9
// 100.410 us; speedup vs baseline: 1.0654x; 1.0654x over previous
//
#include <hip/hip_runtime.h>
#include <hip/hip_bf16.h>

#define NB 16
#define NT 2048
#define NDM 1024
#define NDK 128

typedef __bf16 bf16;
typedef bf16 bf16x4 __attribute__((ext_vector_type(4)));
typedef bf16 bf16x8 __attribute__((ext_vector_type(8)));
typedef float f32x4 __attribute__((ext_vector_type(4)));

__device__ inline bf16 to_bf16(float f) {
    __hip_bfloat16 h = __float2bfloat16(f);
    return *reinterpret_cast<bf16*>(&h);
}

// async 16B global -> LDS (dest: wave-uniform base, HW adds lane*16)
__device__ inline void gload_lds16(const void* g, void* l) {
    __builtin_amdgcn_global_load_lds(
        (const __attribute__((address_space(1))) unsigned int*)g,
        (__attribute__((address_space(3))) unsigned int*)l, 16, 0, 0);
}

// ---------------------------------------------------------------------------
// Kernel 1: W [1024][128] f32  ->  Wt bf16 [3][128][1024]  (transposed, K-major)
// ---------------------------------------------------------------------------
__global__ __launch_bounds__(256) void transpose_w_kernel(
        const float* __restrict__ Wq, const float* __restrict__ Wk,
        const float* __restrict__ Wv, bf16* __restrict__ Wt) {
    int idx = blockIdx.x * 256 + threadIdx.x;      // over 3*1024*128
    int w = idx >> 17;
    int r = idx & (NDM * NDK - 1);
    int k = r >> 7;
    int n = r & (NDK - 1);
    const float* W = (w == 0) ? Wq : ((w == 1) ? Wk : Wv);
    Wt[(size_t)w * NDK * NDM + (size_t)n * NDM + k] = to_bf16(W[(size_t)k * NDK + n]);
}

// ---------------------------------------------------------------------------
// Kernel 2: FUSED QKV projection. One block stages a 128-row x-tile ONCE and
// multiplies by all 3 weight tiles (x HBM traffic cut 3x; MFMA:staging 3x).
// 512 thr / 8 waves (2 row x 4 col), BK=32, dbuf 64KB LDS, acc[3][4][2].
// B staged via global_load_lds (pre-swizzled source); A reg-staged with T14
// split (load before MFMA, convert+ds_write after). XOR swizzle c^=(row>>1)&3.
// V epilogue writes Vt [B][128][T] directly via LDS restage (As/Bs dead).
// ---------------------------------------------------------------------------
__global__ __launch_bounds__(512) void proj_fused_kernel(
        const float* __restrict__ x, const bf16* __restrict__ Wt,
        bf16* __restrict__ qkv, bf16* __restrict__ Vt) {
    // smem: As[2]: 128x32 bf16 (8KB each) @0; Bs[2]: 3x128x32 bf16 (24KB each) @16384
    __shared__ __align__(16) char smem[65536];
    const int tid = threadIdx.x;
    const int lane = tid & 63, wave = tid >> 6;
    const int wr = wave >> 2, wc = wave & 3;
    const int r16 = lane & 15, kg = lane >> 4;
    const int mb = blockIdx.x;
    const float* xA = x + (size_t)mb * 128 * NDM;

    auto ASB = [&](int b) -> bf16* { return (bf16*)(smem + b * 8192); };
    auto BSB = [&](int b) -> bf16* { return (bf16*)(smem + 16384 + b * 24576); };

    // A staging coords: 512 chunks (128 rows x 4), 1/thread. Dest swizzled.
    const int a_row = tid >> 2, a_c = tid & 3;
    const int a_dst = (a_row * 4 + (a_c ^ ((a_row >> 1) & 3))) * 8;  // elem off
    const size_t a_src = (size_t)a_row * NDM + a_c * 8;

    auto loadA = [&](int k0, float4& lo, float4& hi) {
        lo = *reinterpret_cast<const float4*>(xA + a_src + k0);
        hi = *reinterpret_cast<const float4*>(xA + a_src + k0 + 4);
    };
    auto writeA = [&](int buf, const float4& lo, const float4& hi) {
        bf16x8 v;
        v[0] = to_bf16(lo.x); v[1] = to_bf16(lo.y); v[2] = to_bf16(lo.z); v[3] = to_bf16(lo.w);
        v[4] = to_bf16(hi.x); v[5] = to_bf16(hi.y); v[6] = to_bf16(hi.z); v[7] = to_bf16(hi.w);
        *reinterpret_cast<bf16x8*>(ASB(buf) + a_dst) = v;
    };
    // B staging: 1536 chunks (3w x 128 rows x 4), 3/thread, source pre-swizzled
    auto stageB = [&](int buf, int k0) {
#pragma unroll
        for (int p = 0; p < 3; p++) {
            int cid = p * 512 + tid;
            int w = cid >> 9, rem = cid & 511;
            int row = rem >> 2, c = rem & 3;
            int cs = c ^ ((row >> 1) & 3);
            gload_lds16(Wt + (size_t)w * NDK * NDM + (size_t)row * NDM + k0 + cs * 8,
                        BSB(buf) + (p * 512 + wave * 64) * 8);
        }
    };

    f32x4 acc[3][4][2];
#pragma unroll
    for (int w = 0; w < 3; w++)
#pragma unroll
        for (int m = 0; m < 4; m++)
#pragma unroll
            for (int n = 0; n < 2; n++) acc[w][m][n] = (f32x4){0.f, 0.f, 0.f, 0.f};

    // prologue: stage tile 0
    {
        float4 lo, hi;
        loadA(0, lo, hi);
        writeA(0, lo, hi);
        stageB(0, 0);
    }
    __syncthreads();

    for (int kt = 0; kt < NDM / 32; kt++) {
        const int cur = kt & 1;
        const bool pf = (kt + 1 < NDM / 32);
        float4 lo, hi;
        if (pf) {
            loadA((kt + 1) * 32, lo, hi);       // HBM latency hides under MFMA
            stageB(1 - cur, (kt + 1) * 32);     // async direct-to-LDS
        }

        bf16x8 af[4];
#pragma unroll
        for (int m = 0; m < 4; m++) {
            int arow = wr * 64 + m * 16 + r16;
            int ch = kg ^ ((arow >> 1) & 3);
            af[m] = *reinterpret_cast<const bf16x8*>(ASB(cur) + (arow * 4 + ch) * 8);
        }
#pragma unroll
        for (int w = 0; w < 3; w++) {
#pragma unroll
            for (int n = 0; n < 2; n++) {
                int brow = wc * 32 + n * 16 + r16;
                int ch = kg ^ ((brow >> 1) & 3);
                bf16x8 bfw = *reinterpret_cast<const bf16x8*>(
                    BSB(cur) + ((w * 128 + brow) * 4 + ch) * 8);
#pragma unroll
                for (int m = 0; m < 4; m++)
                    acc[w][m][n] = __builtin_amdgcn_mfma_f32_16x16x32_bf16(af[m], bfw, acc[w][m][n], 0, 0, 0);
            }
        }

        if (pf) writeA(1 - cur, lo, hi);   // A regs arrived by now
        __syncthreads();                   // drains gload vmcnt + ds writes
    }

    // epilogue: Q, K planes (scalar stores, as before)
#pragma unroll
    for (int w = 0; w < 2; w++) {
        bf16* outw = qkv + (size_t)w * (size_t)(NB * NT) * NDK;
#pragma unroll
        for (int m = 0; m < 4; m++) {
            int rowb = mb * 128 + wr * 64 + m * 16 + kg * 4;
#pragma unroll
            for (int n = 0; n < 2; n++) {
                int col = wc * 32 + n * 16 + r16;
#pragma unroll
                for (int r = 0; r < 4; r++)
                    outw[(size_t)(rowb + r) * NDK + col] = to_bf16(acc[w][m][n][r]);
            }
        }
    }
    // V: restage transposed in LDS (As/Bs dead), coalesced store to Vt
    bf16 (*Tl)[136] = reinterpret_cast<bf16(*)[136]>(smem);
#pragma unroll
    for (int m = 0; m < 4; m++) {
        int tl = wr * 64 + m * 16 + kg * 4;
#pragma unroll
        for (int n = 0; n < 2; n++) {
            int d = wc * 32 + n * 16 + r16;
            bf16x4 pv = { to_bf16(acc[2][m][n][0]), to_bf16(acc[2][m][n][1]),
                          to_bf16(acc[2][m][n][2]), to_bf16(acc[2][m][n][3]) };
            *reinterpret_cast<bf16x4*>(&Tl[d][tl]) = pv;
        }
    }
    __syncthreads();
    const int b = mb >> 4;
    const int t0 = (mb & 15) * 128;
    bf16* Vb = Vt + (size_t)b * NDK * NT;
#pragma unroll
    for (int p = 0; p < 4; p++) {
        int idx = p * 512 + tid;          // 2048 chunks: 128 d-rows x 16
        int d = idx >> 4, c = idx & 15;
        *reinterpret_cast<bf16x8*>(&Vb[(size_t)d * NT + t0 + c * 8]) =
            *reinterpret_cast<const bf16x8*>(&Tl[d][c * 8]);
    }
}

// ---------------------------------------------------------------------------
// Kernel 3: causal flash attention (unchanged from R7: swapped-QK^T softmax,
// dbuf K/V LDS, 1 barrier/step, reg-prefetch, XCD-pinned batches).
// ---------------------------------------------------------------------------
__global__ __launch_bounds__(256) void attn_kernel(
        const bf16* __restrict__ Q, const bf16* __restrict__ K,
        const bf16* __restrict__ Vt, float* __restrict__ out) {
    __shared__ bf16 Ks[2][64][128];
    __shared__ bf16 Vs[2][128][64];
    __shared__ bf16 Ps[4][16][72];
    const int tid = threadIdx.x, lane = tid & 63, wave = tid >> 6;
    const int r16 = lane & 15, kg = lane >> 4;

    const int bid = blockIdx.x;
    const int xcd = bid & 7;
    const int j = bid >> 3;
    const int b = xcd * 2 + (j & 1);
    const int qb = (NT / 64 - 1) - (j >> 1);
    const int q0 = qb * 64;
    const size_t baseB = (size_t)b * NT * NDK;
    const size_t baseVt = (size_t)b * NDK * NT;

    const float scale = 0.08838834764831843f;
    bf16x8 qf[4];
    const int qglob = q0 + wave * 16 + r16;
#pragma unroll
    for (int kc = 0; kc < 4; kc++) {
        bf16x8 raw = *reinterpret_cast<const bf16x8*>(&Q[baseB + (size_t)qglob * NDK + kc * 32 + kg * 8]);
#pragma unroll
        for (int jj = 0; jj < 8; jj++) raw[jj] = to_bf16((float)raw[jj] * scale);
        qf[kc] = raw;
    }

    f32x4 o[8];
#pragma unroll
    for (int n = 0; n < 8; n++) o[n] = (f32x4){0.f, 0.f, 0.f, 0.f};
    float mrun = -INFINITY;
    float lrun = 0.f;

    int krow[4], kcol[4], vrow[4], vcol[4];
#pragma unroll
    for (int i = 0; i < 4; i++) {
        int idx = i * 256 + tid;
        krow[i] = idx >> 4; kcol[i] = idx & 15;
        vrow[i] = idx >> 3; vcol[i] = idx & 7;
    }

    const int nsteps = qb + 1;
    bf16x8 kreg[4], vreg[4];
#pragma unroll
    for (int i = 0; i < 4; i++) {
        kreg[i] = *reinterpret_cast<const bf16x8*>(&K[baseB + (size_t)krow[i] * NDK + kcol[i] * 8]);
        vreg[i] = *reinterpret_cast<const bf16x8*>(&Vt[baseVt + (size_t)vrow[i] * NT + vcol[i] * 8]);
    }
#pragma unroll
    for (int i = 0; i < 4; i++) {
        *reinterpret_cast<bf16x8*>(&Ks[0][krow[i]][(kcol[i] ^ (krow[i] & 7)) * 8]) = kreg[i];
        *reinterpret_cast<bf16x8*>(&Vs[0][vrow[i]][(vcol[i] ^ (vrow[i] & 7)) * 8]) = vreg[i];
    }
    if (nsteps > 1) {
#pragma unroll
        for (int i = 0; i < 4; i++) {
            kreg[i] = *reinterpret_cast<const bf16x8*>(&K[baseB + (size_t)(64 + krow[i]) * NDK + kcol[i] * 8]);
            vreg[i] = *reinterpret_cast<const bf16x8*>(&Vt[baseVt + (size_t)vrow[i] * NT + 64 + vcol[i] * 8]);
        }
    }
    __syncthreads();

    for (int s = 0; s < nsteps; s++) {
        const int cur = s & 1;
        const int kv0 = s * 64;

        f32x4 sfr[4];
#pragma unroll
        for (int n = 0; n < 4; n++) sfr[n] = (f32x4){0.f, 0.f, 0.f, 0.f};
#pragma unroll
        for (int n = 0; n < 4; n++) {
            const int krw = n * 16 + r16;
#pragma unroll
            for (int kc = 0; kc < 4; kc++) {
                bf16x8 kf = *reinterpret_cast<const bf16x8*>(&Ks[cur][krw][((kc * 4 + kg) ^ (krw & 7)) * 8]);
                sfr[n] = __builtin_amdgcn_mfma_f32_16x16x32_bf16(kf, qf[kc], sfr[n], 0, 0, 0);
            }
        }

        if (s == nsteps - 1) {
#pragma unroll
            for (int n = 0; n < 4; n++)
#pragma unroll
                for (int r = 0; r < 4; r++)
                    if (kv0 + n * 16 + kg * 4 + r > qglob) sfr[n][r] = -INFINITY;
        }

        float pm = -INFINITY;
#pragma unroll
        for (int n = 0; n < 4; n++) {
            float t0 = fmaxf(fmaxf(sfr[n][0], sfr[n][1]), fmaxf(sfr[n][2], sfr[n][3]));
            pm = fmaxf(pm, t0);
        }
        pm = fmaxf(pm, __shfl_xor(pm, 16, 64));
        pm = fmaxf(pm, __shfl_xor(pm, 32, 64));

        if (__any(pm > mrun)) {
            float mnew = fmaxf(mrun, pm);
            float corr = __expf(mrun - mnew);
            mrun = mnew;
            lrun *= corr;
            float co[4];
#pragma unroll
            for (int r = 0; r < 4; r++) co[r] = __shfl(corr, kg * 4 + r, 64);
#pragma unroll
            for (int n = 0; n < 8; n++)
#pragma unroll
                for (int r = 0; r < 4; r++) o[n][r] *= co[r];
        }

        float ps = 0.f;
#pragma unroll
        for (int n = 0; n < 4; n++) {
            bf16x4 pw;
#pragma unroll
            for (int r = 0; r < 4; r++) {
                float pv = __expf(sfr[n][r] - mrun);
                ps += pv;
                pw[r] = to_bf16(pv);
            }
            *reinterpret_cast<bf16x4*>(&Ps[wave][r16][n * 16 + kg * 4]) = pw;
        }
        ps += __shfl_xor(ps, 16, 64);
        ps += __shfl_xor(ps, 32, 64);
        lrun += ps;

#pragma unroll
        for (int kc2 = 0; kc2 < 2; kc2++) {
            bf16x8 pf = *reinterpret_cast<const bf16x8*>(&Ps[wave][r16][kc2 * 32 + kg * 8]);
#pragma unroll
            for (int n = 0; n < 8; n++) {
                const int vrw = n * 16 + r16;
                bf16x8 vf = *reinterpret_cast<const bf16x8*>(&Vs[cur][vrw][((kc2 * 4 + kg) ^ (vrw & 7)) * 8]);
                o[n] = __builtin_amdgcn_mfma_f32_16x16x32_bf16(pf, vf, o[n], 0, 0, 0);
            }
        }

        if (s + 1 < nsteps) {
#pragma unroll
            for (int i = 0; i < 4; i++) {
                *reinterpret_cast<bf16x8*>(&Ks[1 - cur][krow[i]][(kcol[i] ^ (krow[i] & 7)) * 8]) = kreg[i];
                *reinterpret_cast<bf16x8*>(&Vs[1 - cur][vrow[i]][(vcol[i] ^ (vrow[i] & 7)) * 8]) = vreg[i];
            }
            if (s + 2 < nsteps) {
                const int kv2 = (s + 2) * 64;
#pragma unroll
                for (int i = 0; i < 4; i++) {
                    kreg[i] = *reinterpret_cast<const bf16x8*>(&K[baseB + (size_t)(kv2 + krow[i]) * NDK + kcol[i] * 8]);
                    vreg[i] = *reinterpret_cast<const bf16x8*>(&Vt[baseVt + (size_t)vrow[i] * NT + kv2 + vcol[i] * 8]);
                }
            }
        }
        __syncthreads();
    }

    float linv = 1.0f / lrun;
    float li[4];
#pragma unroll
    for (int r = 0; r < 4; r++) li[r] = __shfl(linv, kg * 4 + r, 64);
#pragma unroll
    for (int n = 0; n < 8; n++)
#pragma unroll
        for (int r = 0; r < 4; r++) {
            int row = q0 + wave * 16 + kg * 4 + r;
            int col = n * 16 + r16;
            out[baseB + (size_t)row * NDK + col] = o[n][r] * li[r];
        }
}

// ---------------------------------------------------------------------------
extern "C" void kernel_launch(void* const* d_in, const int* in_sizes, int n_in,
                              void* d_out, int out_size, void* d_ws, size_t ws_size,
                              hipStream_t stream) {
    const float* x  = (const float*)d_in[0];
    const float* Wq = (const float*)d_in[1];
    const float* Wk = (const float*)d_in[2];
    const float* Wv = (const float*)d_in[3];
    float* out = (float*)d_out;

    char* ws = (char*)d_ws;
    bf16* Wt  = (bf16*)ws;                        // 768 KB
    bf16* qkv = (bf16*)(ws + (1ull << 20));       // Q,K planes: 16 MB
    bf16* Vtg = (bf16*)(ws + (26ull << 20));      // V^T [B][128][T]: 8 MB

    transpose_w_kernel<<<(3 * NDM * NDK) / 256, 256, 0, stream>>>(Wq, Wk, Wv, Wt);

    // fused QKV projection: x staged once, 3 weight tiles; V written transposed
    proj_fused_kernel<<<(NB * NT) / 128, 512, 0, stream>>>(x, Wt, qkv, Vtg);

    bf16* Qp = qkv;
    bf16* Kp = qkv + (size_t)(NB * NT) * NDK;

    attn_kernel<<<dim3((NT / 64) * NB), 256, 0, stream>>>(Qp, Kp, Vtg, out);
}